// Round 1
// baseline (502.469 us; speedup 1.0000x reference)
//
#include <hip/hip_runtime.h>
#include <math.h>

#define B_ 2
#define T_ 2048
#define E_ 512
#define H_ 8
#define D_ 64
#define NCH 16
#define CH 128
#define EPS_ 1e-5f

// ---------------- GEMM: C[4096,512] = A[4096,512] @ W[512,512] (f32) ----------------
__global__ __launch_bounds__(256) void gemm512(const float* __restrict__ A,
                                               const float* __restrict__ W,
                                               float* __restrict__ C) {
  __shared__ float As[16][68];
  __shared__ float Bs[16][68];
  const int tid = threadIdx.x;
  const int tx = tid & 15, ty = tid >> 4;
  const int row0 = blockIdx.x * 64, col0 = blockIdx.y * 64;
  const int lr = tid >> 2, lk = (tid & 3) * 4;
  const int bkr = tid >> 4, bcc = (tid & 15) * 4;
  float acc[4][4] = {};
  for (int k0 = 0; k0 < 512; k0 += 16) {
    float4 a4 = *(const float4*)(A + (size_t)(row0 + lr) * 512 + k0 + lk);
    As[lk + 0][lr] = a4.x; As[lk + 1][lr] = a4.y;
    As[lk + 2][lr] = a4.z; As[lk + 3][lr] = a4.w;
    *(float4*)&Bs[bkr][bcc] = *(const float4*)(W + (size_t)(k0 + bkr) * 512 + col0 + bcc);
    __syncthreads();
#pragma unroll
    for (int kk = 0; kk < 16; ++kk) {
      float4 av = *(const float4*)&As[kk][ty * 4];
      float4 bv = *(const float4*)&Bs[kk][tx * 4];
      float aa[4] = {av.x, av.y, av.z, av.w};
      float bb[4] = {bv.x, bv.y, bv.z, bv.w};
#pragma unroll
      for (int i = 0; i < 4; ++i)
#pragma unroll
        for (int j = 0; j < 4; ++j) acc[i][j] += aa[i] * bb[j];
    }
    __syncthreads();
  }
#pragma unroll
  for (int i = 0; i < 4; ++i) {
    float4 o = make_float4(acc[i][0], acc[i][1], acc[i][2], acc[i][3]);
    *(float4*)(C + (size_t)(row0 + ty * 4 + i) * 512 + col0 + tx * 4) = o;
  }
}

// ---------------- features: normalize + FAVOR (E) + TensorSketch (T), plus v relayout ----------------
__global__ __launch_bounds__(128) void feat_kernel(
    const float* __restrict__ q, const float* __restrict__ k, const float* __restrict__ v,
    const float* __restrict__ proj, const float* __restrict__ scales,
    const int* __restrict__ sh, const float* __restrict__ ss,
    float* __restrict__ Tq, float* __restrict__ Eq,
    float* __restrict__ Tk, float* __restrict__ Ek, float* __restrict__ vh) {
  __shared__ float pj[64][64];   // [s*16+m][d]
  __shared__ float sq2t[4], m2t[4], cf[4];
  __shared__ int h1[64], h2[64];
  __shared__ float s1[64], s2[64];
  const int tid = threadIdx.x;
  for (int i = tid; i < 4096; i += 128) pj[i >> 6][i & 63] = proj[i];
  if (tid < 4) {
    float t = scales[tid * 2], c = scales[tid * 2 + 1];
    sq2t[tid] = sqrtf(2.f * t); m2t[tid] = -2.f * t; cf[tid] = sqrtf(c / 16.f);
  }
  if (tid < 64) { h1[tid] = sh[tid]; h2[tid] = sh[64 + tid]; s1[tid] = ss[tid]; s2[tid] = ss[64 + tid]; }
  __syncthreads();
  const int isK = blockIdx.y;
  const int row = blockIdx.x * 128 + tid;      // (b*T + t)*H + h
  const int h = row & 7; const int bt = row >> 3;
  const int t = bt & (T_ - 1); const int b = bt >> 11;
  const size_t src = (size_t)bt * 512 + h * 64;
  const size_t orow = (size_t)(b * H_ + h) * T_ + t;
  const float* in = (isK ? k : q) + src;
  float* To = (isK ? Tk : Tq) + orow * 16;
  float* Eo = (isK ? Ek : Eq) + orow * 64;

  float u[64]; float nrm = 0.f;
#pragma unroll
  for (int d = 0; d < 64; ++d) { float xv = in[d]; u[d] = xv; nrm += xv * xv; }
  const float inv = 1.f / (sqrtf(nrm) + 1e-6f);
#pragma unroll
  for (int d = 0; d < 64; ++d) u[d] *= inv;

  // TensorSketch: p1/p2 via static-index selection (no runtime-indexed arrays)
  float p1[16], p2[16];
#pragma unroll
  for (int j = 0; j < 16; ++j) {
    float a1 = 0.f, a2 = 0.f;
#pragma unroll
    for (int d = 0; d < 64; ++d) {
      a1 += (h1[d] == j ? s1[d] : 0.f) * u[d];
      a2 += (h2[d] == j ? s2[d] : 0.f) * u[d];
    }
    p1[j] = a1; p2[j] = a2;
  }
  float tsv[16];
#pragma unroll
  for (int r = 0; r < 16; ++r) {
    float a = 0.f;
#pragma unroll
    for (int j = 0; j < 16; ++j) a += p1[j] * p2[(r - j) & 15];
    tsv[r] = a;
  }
#pragma unroll
  for (int p = 0; p < 16; ++p) To[p] = tsv[p];

  // FAVOR features
#pragma unroll
  for (int s = 0; s < 4; ++s) {
    const float sq = sq2t[s], mb = m2t[s], c = cf[s];
#pragma unroll
    for (int m = 0; m < 16; ++m) {
      float z = 0.f;
      const float* pr = &pj[s * 16 + m][0];
#pragma unroll
      for (int d = 0; d < 64; ++d) z += pr[d] * u[d];
      Eo[s * 16 + m] = expf(sq * z + mb) * c;
    }
  }

  // v relayout [b,t,h,d] -> [b,h,t,d] (done by the q-pass blocks)
  if (!isK) {
    const size_t bt0 = (size_t)blockIdx.x * 16;
    for (int i = tid; i < 16 * 512; i += 128) {
      const size_t bt2 = bt0 + (i >> 9);
      const int hh = (i >> 6) & 7, dd = i & 63;
      const int t2 = (int)(bt2 & (T_ - 1)); const int b2 = (int)(bt2 >> 11);
      vh[((size_t)(b2 * H_ + hh) * T_ + t2) * 64 + dd] = v[bt0 * 512 + i];
    }
  }
}

// ---------------- per-chunk KV[p,e,d] (e-slice of 16 per block) ----------------
__global__ __launch_bounds__(256) void kv_kernel(const float* __restrict__ Tk, const float* __restrict__ Ek,
                                                 const float* __restrict__ vh, float* __restrict__ KV) {
  const int bhn = blockIdx.x;      // bh*16 + n
  const int slice = blockIdx.y;    // e0 = slice*16
  __shared__ float tks[128][16];
  __shared__ float eks[128][16];
  __shared__ float vs[128][64];
  const int tid = threadIdx.x;
  const size_t rowbase = (size_t)bhn * 128;
  for (int i = tid; i < 2048; i += 256) tks[i >> 4][i & 15] = Tk[rowbase * 16 + i];
  for (int i = tid; i < 2048; i += 256) { int r = i >> 4, e = i & 15; eks[r][e] = Ek[(rowbase + r) * 64 + slice * 16 + e]; }
  for (int i = tid; i < 8192; i += 256) vs[i >> 6][i & 63] = vh[rowbase * 64 + i];
  __syncthreads();
  const int d = tid & 63, er = tid >> 6;
  float acc[4][16] = {};
  for (int c = 0; c < 128; ++c) {
    float tkc[16];
#pragma unroll
    for (int p = 0; p < 16; ++p) tkc[p] = tks[c][p];
    const float w = vs[c][d];
#pragma unroll
    for (int i = 0; i < 4; ++i) {
      const float a = eks[c][er * 4 + i] * w;
#pragma unroll
      for (int p = 0; p < 16; ++p) acc[i][p] += tkc[p] * a;
    }
  }
  float* out = KV + (size_t)bhn * 65536;
#pragma unroll
  for (int i = 0; i < 4; ++i)
#pragma unroll
    for (int p = 0; p < 16; ++p)
      out[(size_t)(p * 64 + slice * 16 + er * 4 + i) * 64 + d] = acc[i][p];
}

// ---------------- per-chunk KZ[p,e] ----------------
__global__ __launch_bounds__(256) void kz_kernel(const float* __restrict__ Tk, const float* __restrict__ Ek,
                                                 float* __restrict__ KZ) {
  const int bhn = blockIdx.x;
  __shared__ float tks[128][16];
  __shared__ float eks[128][64];
  const int tid = threadIdx.x;
  const size_t rowbase = (size_t)bhn * 128;
  for (int i = tid; i < 2048; i += 256) tks[i >> 4][i & 15] = Tk[rowbase * 16 + i];
  for (int i = tid; i < 8192; i += 256) eks[i >> 6][i & 63] = Ek[rowbase * 64 + i];
  __syncthreads();
  float acc[4] = {};
  for (int c = 0; c < 128; ++c) {
#pragma unroll
    for (int i = 0; i < 4; ++i) {
      const int item = tid + 256 * i;
      acc[i] += tks[c][item >> 6] * eks[c][item & 63];
    }
  }
#pragma unroll
  for (int i = 0; i < 4; ++i) KZ[(size_t)bhn * 1024 + tid + 256 * i] = acc[i];
}

// ---------------- exclusive cumsum over chunks (in place) ----------------
__global__ void cumsum_kernel(float* __restrict__ KV, float* __restrict__ KZ) {
  const size_t idx = (size_t)blockIdx.x * 256 + threadIdx.x;
  const size_t nkv = (size_t)B_ * H_ * 65536;
  if (idx < nkv) {
    const size_t bh = idx >> 16, j = idx & 65535;
    float* p = KV + bh * NCH * 65536 + j;
    float a = 0.f;
#pragma unroll
    for (int n = 0; n < NCH; ++n) { const float t = p[(size_t)n << 16]; p[(size_t)n << 16] = a; a += t; }
  } else {
    const size_t i2 = idx - nkv;
    if (i2 < (size_t)B_ * H_ * 1024) {
      const size_t bh = i2 >> 10, j = i2 & 1023;
      float* p = KZ + bh * NCH * 1024 + j;
      float a = 0.f;
#pragma unroll
      for (int n = 0; n < NCH; ++n) { const float t = p[n << 10]; p[n << 10] = a; a += t; }
    }
  }
}

// ---------------- intra-chunk causal part: sc = (Tq.Tk)*(Eq.Ek), num_intra, den_intra ----------------
__global__ __launch_bounds__(256) void intra_kernel(const float* __restrict__ Tq, const float* __restrict__ Eq,
                                                    const float* __restrict__ Tk, const float* __restrict__ Ek,
                                                    const float* __restrict__ vh,
                                                    float* __restrict__ numb, float* __restrict__ den) {
  const int bhn = blockIdx.x;
  __shared__ float tks[64][16];
  __shared__ float eks[64][64];
  __shared__ float vs[64][64];
  const int tid = threadIdx.x;
  const int c = tid >> 1, half = tid & 1;
  const size_t rowbase = (size_t)bhn * 128;
  const size_t myrow = rowbase + c;
  float tq[16], eq[64];
#pragma unroll
  for (int p = 0; p < 16; ++p) tq[p] = Tq[myrow * 16 + p];
#pragma unroll
  for (int e = 0; e < 64; ++e) eq[e] = Eq[myrow * 64 + e];
  float num[32] = {};
  float dn = 0.f;
  for (int kh = 0; kh < 2; ++kh) {
    __syncthreads();
    for (int i = tid; i < 1024; i += 256) tks[i >> 4][i & 15] = Tk[(rowbase + kh * 64) * 16 + i];
    for (int i = tid; i < 4096; i += 256) eks[i >> 6][i & 63] = Ek[(rowbase + kh * 64) * 64 + i];
    for (int i = tid; i < 4096; i += 256) vs[i >> 6][i & 63] = vh[(rowbase + kh * 64) * 64 + i];
    __syncthreads();
    const int kmax = c - kh * 64;
    for (int kk = 0; kk < 64; ++kk) {
      if (kk > kmax) break;
      float dT = 0.f;
#pragma unroll
      for (int p = 0; p < 16; ++p) dT += tq[p] * tks[kk][p];
      float dE = 0.f;
#pragma unroll
      for (int e = 0; e < 64; ++e) dE += eq[e] * eks[kk][e];
      const float s = dT * dE;
      dn += s;
#pragma unroll
      for (int j = 0; j < 32; ++j) num[j] += s * vs[kk][half * 32 + j];
    }
  }
#pragma unroll
  for (int j = 0; j < 32; ++j) numb[myrow * 64 + half * 32 + j] = num[j];
  if (half == 0) den[myrow] = dn;
}

// ---------------- inter-chunk part + finalize out = num/(den+eps), relayout for Wo ----------------
__global__ __launch_bounds__(256) void inter_kernel(const float* __restrict__ Tq, const float* __restrict__ Eq,
                                                    const float* __restrict__ KV, const float* __restrict__ KZ,
                                                    const float* __restrict__ numb, const float* __restrict__ den,
                                                    float* __restrict__ att) {
  const int bhn = blockIdx.x;
  const int n = bhn & 15, bh = bhn >> 4;
  const int b = bh >> 3, h = bh & 7;
  __shared__ float tqs[128][17];
  __shared__ float eqs[128][68];
  __shared__ float kvp[64][68];
  __shared__ float kzp[64];
  const int tid = threadIdx.x;
  const int tx = tid & 15, ty = tid >> 4;
  const size_t rowbase = (size_t)bhn * 128;
  for (int i = tid; i < 2048; i += 256) tqs[i >> 4][i & 15] = Tq[rowbase * 16 + i];
  for (int i = tid; i < 8192; i += 256) eqs[i >> 6][i & 63] = Eq[rowbase * 64 + i];
  float acc[8][4] = {};
  float accd[8] = {};
  const float* kvb = KV + (size_t)bhn * 65536;
  for (int p = 0; p < 16; ++p) {
    __syncthreads();
    for (int i = tid; i < 4096; i += 256) kvp[i >> 6][i & 63] = kvb[p * 4096 + i];
    if (tid < 64) kzp[tid] = KZ[(size_t)bhn * 1024 + p * 64 + tid];
    __syncthreads();
    float tqv[8];
#pragma unroll
    for (int ci = 0; ci < 8; ++ci) tqv[ci] = tqs[ty + 16 * ci][p];
    for (int e = 0; e < 64; ++e) {
      const float4 kv4 = *(const float4*)&kvp[e][tx * 4];
      const float kz = kzp[e];
#pragma unroll
      for (int ci = 0; ci < 8; ++ci) {
        const float a = tqv[ci] * eqs[ty + 16 * ci][e];
        acc[ci][0] += a * kv4.x; acc[ci][1] += a * kv4.y;
        acc[ci][2] += a * kv4.z; acc[ci][3] += a * kv4.w;
        accd[ci] += a * kz;
      }
    }
  }
#pragma unroll
  for (int ci = 0; ci < 8; ++ci) {
    const int cc = ty + 16 * ci;
    const size_t row = rowbase + cc;
    const int t = n * 128 + cc;
    const float invd = 1.f / (den[row] + accd[ci] + EPS_);
    float4 o;
    o.x = (numb[row * 64 + tx * 4 + 0] + acc[ci][0]) * invd;
    o.y = (numb[row * 64 + tx * 4 + 1] + acc[ci][1]) * invd;
    o.z = (numb[row * 64 + tx * 4 + 2] + acc[ci][2]) * invd;
    o.w = (numb[row * 64 + tx * 4 + 3] + acc[ci][3]) * invd;
    *(float4*)(att + (size_t)(b * T_ + t) * 512 + h * 64 + tx * 4) = o;
  }
}

extern "C" void kernel_launch(void* const* d_in, const int* in_sizes, int n_in,
                              void* d_out, int out_size, void* d_ws, size_t ws_size,
                              hipStream_t stream) {
  const float* x   = (const float*)d_in[0];
  const float* Wq  = (const float*)d_in[1];
  const float* Wk  = (const float*)d_in[2];
  const float* Wv  = (const float*)d_in[3];
  const float* Wo  = (const float*)d_in[4];
  const float* prj = (const float*)d_in[5];
  const float* scl = (const float*)d_in[6];
  const int*   shh = (const int*)d_in[7];
  const float* sss = (const float*)d_in[8];

  float* ws  = (float*)d_ws;
  float* q   = ws;                 // [B,T,H,D] as [4096,512]
  float* k   = q + 2097152;
  float* v   = k + 2097152;
  float* Tq  = v + 2097152;        // [B,H,T,16]
  float* Eq  = Tq + 524288;        // [B,H,T,64]
  float* Tk  = Eq + 2097152;
  float* Ek  = Tk + 524288;
  float* vh  = Ek + 2097152;       // [B,H,T,64]
  float* KV  = vh + 2097152;       // [B,H,N,16,64,64]
  float* KZ  = KV + 16777216;      // [B,H,N,16,64]
  float* nmb = KZ + 262144;        // [B,H,T,64]
  float* den = nmb + 2097152;      // [B,H,T]
  float* att = den + 32768;        // [B,T,512]

  dim3 gg(64, 8);
  hipLaunchKernelGGL(gemm512, gg, dim3(256), 0, stream, x, Wq, q);
  hipLaunchKernelGGL(gemm512, gg, dim3(256), 0, stream, x, Wk, k);
  hipLaunchKernelGGL(gemm512, gg, dim3(256), 0, stream, x, Wv, v);
  hipLaunchKernelGGL(feat_kernel, dim3(256, 2), dim3(128), 0, stream,
                     q, k, v, prj, scl, shh, sss, Tq, Eq, Tk, Ek, vh);
  hipLaunchKernelGGL(kv_kernel, dim3(256, 4), dim3(256), 0, stream, Tk, Ek, vh, KV);
  hipLaunchKernelGGL(kz_kernel, dim3(256), dim3(256), 0, stream, Tk, Ek, KZ);
  hipLaunchKernelGGL(cumsum_kernel, dim3(4160), dim3(256), 0, stream, KV, KZ);
  hipLaunchKernelGGL(intra_kernel, dim3(256), dim3(256), 0, stream, Tq, Eq, Tk, Ek, vh, nmb, den);
  hipLaunchKernelGGL(inter_kernel, dim3(256), dim3(256), 0, stream, Tq, Eq, KV, KZ, nmb, den, att);
  hipLaunchKernelGGL(gemm512, gg, dim3(256), 0, stream, att, Wo, (float*)d_out);
}

// Round 4
// 481.007 us; speedup vs baseline: 1.0446x; 1.0446x over previous
//
#include <hip/hip_runtime.h>
#include <math.h>

#define B_ 2
#define T_ 2048
#define E_ 512
#define H_ 8
#define D_ 64
#define NCH 16
#define CH 128
#define EPS_ 1e-5f

// ---------------- GEMM: C[4096,512] = A[4096,512] @ W[512,512] (f32) ----------------
__global__ __launch_bounds__(256) void gemm512(const float* __restrict__ A,
                                               const float* __restrict__ W,
                                               float* __restrict__ C) {
  __shared__ float As[16][68];
  __shared__ float Bs[16][68];
  const int tid = threadIdx.x;
  const int tx = tid & 15, ty = tid >> 4;
  const int row0 = blockIdx.x * 64, col0 = blockIdx.y * 64;
  const int lr = tid >> 2, lk = (tid & 3) * 4;
  const int bkr = tid >> 4, bcc = (tid & 15) * 4;
  float acc[4][4] = {};
  for (int k0 = 0; k0 < 512; k0 += 16) {
    float4 a4 = *(const float4*)(A + (size_t)(row0 + lr) * 512 + k0 + lk);
    As[lk + 0][lr] = a4.x; As[lk + 1][lr] = a4.y;
    As[lk + 2][lr] = a4.z; As[lk + 3][lr] = a4.w;
    *(float4*)&Bs[bkr][bcc] = *(const float4*)(W + (size_t)(k0 + bkr) * 512 + col0 + bcc);
    __syncthreads();
#pragma unroll
    for (int kk = 0; kk < 16; ++kk) {
      float4 av = *(const float4*)&As[kk][ty * 4];
      float4 bv = *(const float4*)&Bs[kk][tx * 4];
      float aa[4] = {av.x, av.y, av.z, av.w};
      float bb[4] = {bv.x, bv.y, bv.z, bv.w};
#pragma unroll
      for (int i = 0; i < 4; ++i)
#pragma unroll
        for (int j = 0; j < 4; ++j) acc[i][j] += aa[i] * bb[j];
    }
    __syncthreads();
  }
#pragma unroll
  for (int i = 0; i < 4; ++i) {
    float4 o = make_float4(acc[i][0], acc[i][1], acc[i][2], acc[i][3]);
    *(float4*)(C + (size_t)(row0 + ty * 4 + i) * 512 + col0 + tx * 4) = o;
  }
}

// ---------------- features: normalize + FAVOR (E) + TensorSketch (T), plus v relayout ----------------
__global__ __launch_bounds__(128) void feat_kernel(
    const float* __restrict__ q, const float* __restrict__ k, const float* __restrict__ v,
    const float* __restrict__ proj, const float* __restrict__ scales,
    const int* __restrict__ sh, const float* __restrict__ ss,
    float* __restrict__ Tq, float* __restrict__ Eq,
    float* __restrict__ Tk, float* __restrict__ Ek, float* __restrict__ vh) {
  __shared__ float pj[64][64];   // [s*16+m][d]
  __shared__ float sq2t[4], m2t[4], cf[4];
  __shared__ int h1[64], h2[64];
  __shared__ float s1[64], s2[64];
  const int tid = threadIdx.x;
  for (int i = tid; i < 4096; i += 128) pj[i >> 6][i & 63] = proj[i];
  if (tid < 4) {
    float t = scales[tid * 2], c = scales[tid * 2 + 1];
    sq2t[tid] = sqrtf(2.f * t); m2t[tid] = -2.f * t; cf[tid] = sqrtf(c / 16.f);
  }
  if (tid < 64) { h1[tid] = sh[tid]; h2[tid] = sh[64 + tid]; s1[tid] = ss[tid]; s2[tid] = ss[64 + tid]; }
  __syncthreads();
  const int isK = blockIdx.y;
  const int row = blockIdx.x * 128 + tid;      // (b*T + t)*H + h
  const int h = row & 7; const int bt = row >> 3;
  const int t = bt & (T_ - 1); const int b = bt >> 11;
  const size_t src = (size_t)bt * 512 + h * 64;
  const size_t orow = (size_t)(b * H_ + h) * T_ + t;
  const float* in = (isK ? k : q) + src;
  float* To = (isK ? Tk : Tq) + orow * 16;
  float* Eo = (isK ? Ek : Eq) + orow * 64;

  float u[64]; float nrm = 0.f;
#pragma unroll
  for (int d = 0; d < 64; ++d) { float xv = in[d]; u[d] = xv; nrm += xv * xv; }
  const float inv = 1.f / (sqrtf(nrm) + 1e-6f);
#pragma unroll
  for (int d = 0; d < 64; ++d) u[d] *= inv;

  float p1[16], p2[16];
#pragma unroll
  for (int j = 0; j < 16; ++j) {
    float a1 = 0.f, a2 = 0.f;
#pragma unroll
    for (int d = 0; d < 64; ++d) {
      a1 += (h1[d] == j ? s1[d] : 0.f) * u[d];
      a2 += (h2[d] == j ? s2[d] : 0.f) * u[d];
    }
    p1[j] = a1; p2[j] = a2;
  }
  float tsv[16];
#pragma unroll
  for (int r = 0; r < 16; ++r) {
    float a = 0.f;
#pragma unroll
    for (int j = 0; j < 16; ++j) a += p1[j] * p2[(r - j) & 15];
    tsv[r] = a;
  }
#pragma unroll
  for (int p = 0; p < 16; ++p) To[p] = tsv[p];

#pragma unroll
  for (int s = 0; s < 4; ++s) {
    const float sq = sq2t[s], mb = m2t[s], c = cf[s];
#pragma unroll
    for (int m = 0; m < 16; ++m) {
      float z = 0.f;
      const float* pr = &pj[s * 16 + m][0];
#pragma unroll
      for (int d = 0; d < 64; ++d) z += pr[d] * u[d];
      Eo[s * 16 + m] = expf(sq * z + mb) * c;
    }
  }

  if (!isK) {
    const size_t bt0 = (size_t)blockIdx.x * 16;
    for (int i = tid; i < 16 * 512; i += 128) {
      const size_t bt2 = bt0 + (i >> 9);
      const int hh = (i >> 6) & 7, dd = i & 63;
      const int t2 = (int)(bt2 & (T_ - 1)); const int b2 = (int)(bt2 >> 11);
      vh[((size_t)(b2 * H_ + hh) * T_ + t2) * 64 + dd] = v[bt0 * 512 + i];
    }
  }
}

// ---------------- per-chunk KV[p,e,d] (e-slice of 16 per block), vectorized LDS ----------------
__global__ __launch_bounds__(256) void kv_kernel(const float* __restrict__ Tk, const float* __restrict__ Ek,
                                                 const float* __restrict__ vh, float* __restrict__ KV) {
  const int bhn = blockIdx.x;      // bh*16 + n
  const int slice = blockIdx.y;    // e0 = slice*16
  __shared__ float tks[128][20];   // pad 20: float4-aligned rows
  __shared__ float eks[128][16];
  __shared__ float vs[128][64];
  const int tid = threadIdx.x;
  const size_t rowbase = (size_t)bhn * 128;
  for (int i = tid; i < 2048; i += 256) tks[i >> 4][i & 15] = Tk[rowbase * 16 + i];
  for (int i = tid; i < 2048; i += 256) { int r = i >> 4, e = i & 15; eks[r][e] = Ek[(rowbase + r) * 64 + slice * 16 + e]; }
  for (int i = tid; i < 2048; i += 256) {
    float4 v4 = *(const float4*)(vh + rowbase * 64 + 4 * i);
    *(float4*)&vs[(4 * i) >> 6][(4 * i) & 63] = v4;
  }
  __syncthreads();
  const int d = tid & 63, er = tid >> 6;
  float acc[4][16] = {};
  for (int c = 0; c < 128; ++c) {
    float4 t0 = *(const float4*)&tks[c][0];
    float4 t1 = *(const float4*)&tks[c][4];
    float4 t2 = *(const float4*)&tks[c][8];
    float4 t3 = *(const float4*)&tks[c][12];
    float tkc[16] = {t0.x, t0.y, t0.z, t0.w, t1.x, t1.y, t1.z, t1.w,
                     t2.x, t2.y, t2.z, t2.w, t3.x, t3.y, t3.z, t3.w};
    float4 e4 = *(const float4*)&eks[c][er * 4];
    const float w = vs[c][d];
    float ai[4] = {e4.x * w, e4.y * w, e4.z * w, e4.w * w};
#pragma unroll
    for (int i = 0; i < 4; ++i)
#pragma unroll
      for (int p = 0; p < 16; ++p) acc[i][p] += tkc[p] * ai[i];
  }
  float* out = KV + (size_t)bhn * 65536;
#pragma unroll
  for (int i = 0; i < 4; ++i)
#pragma unroll
    for (int p = 0; p < 16; ++p)
      out[(size_t)(p * 64 + slice * 16 + er * 4 + i) * 64 + d] = acc[i][p];
}

// ---------------- per-chunk KZ[p,e] ----------------
__global__ __launch_bounds__(256) void kz_kernel(const float* __restrict__ Tk, const float* __restrict__ Ek,
                                                 float* __restrict__ KZ) {
  const int bhn = blockIdx.x;
  __shared__ float tks[128][20];
  __shared__ float eks[128][64];
  const int tid = threadIdx.x;
  const size_t rowbase = (size_t)bhn * 128;
  for (int i = tid; i < 2048; i += 256) tks[i >> 4][i & 15] = Tk[rowbase * 16 + i];
  for (int i = tid; i < 2048; i += 256) {
    float4 v4 = *(const float4*)(Ek + rowbase * 64 + 4 * i);
    *(float4*)&eks[(4 * i) >> 6][(4 * i) & 63] = v4;
  }
  __syncthreads();
  const int e = tid & 63, p0 = (tid >> 6) * 4;
  float a[4] = {};
  for (int c = 0; c < 128; ++c) {
    float4 t4 = *(const float4*)&tks[c][p0];
    const float ek = eks[c][e];
    a[0] += t4.x * ek; a[1] += t4.y * ek; a[2] += t4.z * ek; a[3] += t4.w * ek;
  }
#pragma unroll
  for (int j = 0; j < 4; ++j) KZ[(size_t)bhn * 1024 + (p0 + j) * 64 + e] = a[j];
}

// ---------------- exclusive cumsum over chunks (in place) ----------------
__global__ void cumsum_kernel(float* __restrict__ KV, float* __restrict__ KZ) {
  const size_t idx = (size_t)blockIdx.x * 256 + threadIdx.x;
  const size_t nkv = (size_t)B_ * H_ * 65536;
  if (idx < nkv) {
    const size_t bh = idx >> 16, j = idx & 65535;
    float* p = KV + bh * NCH * 65536 + j;
    float a = 0.f;
#pragma unroll
    for (int n = 0; n < NCH; ++n) { const float t = p[(size_t)n << 16]; p[(size_t)n << 16] = a; a += t; }
  } else {
    const size_t i2 = idx - nkv;
    if (i2 < (size_t)B_ * H_ * 1024) {
      const size_t bh = i2 >> 10, j = i2 & 1023;
      float* p = KZ + bh * NCH * 1024 + j;
      float a = 0.f;
#pragma unroll
      for (int n = 0; n < NCH; ++n) { const float t = p[n << 10]; p[n << 10] = a; a += t; }
    }
  }
}

// ---------------- intra-chunk causal part, single-sync safe version ----------------
// grid (256 bhn, 2 rh); 256 threads; 4 threads per q-row, each owns 16 d-cols.
// One __syncthreads() after staging; no LDS writes afterwards -> race-free by construction.
__global__ __launch_bounds__(256) void intra_kernel(const float* __restrict__ Tq, const float* __restrict__ Eq,
                                                    const float* __restrict__ Tk, const float* __restrict__ Ek,
                                                    const float* __restrict__ vh,
                                                    float* __restrict__ numb, float* __restrict__ den) {
  const int bhn = blockIdx.x;
  const int rh = blockIdx.y;
  __shared__ float tks[128][20];   // [k][p], padded
  __shared__ float eks[128][68];   // [k][e], padded
  __shared__ float vs[128][68];    // [k][d], padded
  const int tid = threadIdx.x;
  const int r = tid >> 2, dg = tid & 3, d0 = dg * 16;
  const int nk = (rh + 1) * 64;            // k rows needed (block-uniform)
  const size_t chunkbase = (size_t)bhn * 128;
  const size_t myrow = chunkbase + rh * 64 + r;

  for (int i = tid; i < nk * 16; i += 256) tks[i >> 4][i & 15] = Tk[chunkbase * 16 + i];
  for (int i = tid; i < nk * 16; i += 256) {
    float4 e4 = *(const float4*)(Ek + chunkbase * 64 + 4 * i);
    *(float4*)&eks[(4 * i) >> 6][(4 * i) & 63] = e4;
    float4 w4 = *(const float4*)(vh + chunkbase * 64 + 4 * i);
    *(float4*)&vs[(4 * i) >> 6][(4 * i) & 63] = w4;
  }
  float tq[16], eq[64];
#pragma unroll
  for (int pp = 0; pp < 4; ++pp) {
    float4 t4 = *(const float4*)(Tq + myrow * 16 + pp * 4);
    tq[pp * 4 + 0] = t4.x; tq[pp * 4 + 1] = t4.y; tq[pp * 4 + 2] = t4.z; tq[pp * 4 + 3] = t4.w;
  }
#pragma unroll
  for (int ee = 0; ee < 16; ++ee) {
    float4 e4 = *(const float4*)(Eq + myrow * 64 + ee * 4);
    eq[ee * 4 + 0] = e4.x; eq[ee * 4 + 1] = e4.y; eq[ee * 4 + 2] = e4.z; eq[ee * 4 + 3] = e4.w;
  }
  __syncthreads();

  float num[16] = {};
  float dn = 0.f;
  const int kmax = rh * 64 + r;            // inclusive causal bound
  for (int kk = 0; kk <= kmax; ++kk) {
    float dT = 0.f, dE = 0.f;
#pragma unroll
    for (int pp = 0; pp < 4; ++pp) {
      float4 t4 = *(const float4*)&tks[kk][pp * 4];
      dT += tq[pp * 4 + 0] * t4.x + tq[pp * 4 + 1] * t4.y + tq[pp * 4 + 2] * t4.z + tq[pp * 4 + 3] * t4.w;
    }
#pragma unroll
    for (int ee = 0; ee < 16; ++ee) {
      float4 e4 = *(const float4*)&eks[kk][ee * 4];
      dE += eq[ee * 4 + 0] * e4.x + eq[ee * 4 + 1] * e4.y + eq[ee * 4 + 2] * e4.z + eq[ee * 4 + 3] * e4.w;
    }
    const float s = dT * dE;
    dn += s;
#pragma unroll
    for (int jj = 0; jj < 4; ++jj) {
      float4 v4 = *(const float4*)&vs[kk][d0 + jj * 4];
      num[jj * 4 + 0] += s * v4.x; num[jj * 4 + 1] += s * v4.y;
      num[jj * 4 + 2] += s * v4.z; num[jj * 4 + 3] += s * v4.w;
    }
  }
#pragma unroll
  for (int jj = 0; jj < 4; ++jj) {
    float4 o = make_float4(num[jj * 4 + 0], num[jj * 4 + 1], num[jj * 4 + 2], num[jj * 4 + 3]);
    *(float4*)(numb + myrow * 64 + d0 + jj * 4) = o;
  }
  if (dg == 0) den[myrow] = dn;
}

// ---------------- inter-chunk part + finalize, single-buffered safe version ----------------
// grid (256 bhn, 2 rh); 64 rows/block; p-loop: sync -> stage -> sync -> compute.
__global__ __launch_bounds__(256) void inter_kernel(const float* __restrict__ Tq, const float* __restrict__ Eq,
                                                    const float* __restrict__ KV, const float* __restrict__ KZ,
                                                    const float* __restrict__ numb, const float* __restrict__ den,
                                                    float* __restrict__ att) {
  const int bhn = blockIdx.x;
  const int rh = blockIdx.y;
  const int n = bhn & 15, bh = bhn >> 4;
  const int b = bh >> 3, h = bh & 7;
  __shared__ float tqs[64][17];
  __shared__ float eqs[64][68];
  __shared__ float kvp[64][68];
  __shared__ float kzp[64];
  const int tid = threadIdx.x;
  const int tx = tid & 15, ty = tid >> 4;
  const size_t rowbase = (size_t)bhn * 128 + rh * 64;
  for (int i = tid; i < 1024; i += 256) tqs[i >> 4][i & 15] = Tq[rowbase * 16 + i];
  for (int i = tid; i < 1024; i += 256) {
    float4 v4 = *(const float4*)(Eq + rowbase * 64 + 4 * i);
    *(float4*)&eqs[i >> 4][(i & 15) * 4] = v4;
  }
  const float* kvb = KV + (size_t)bhn * 65536;
  const float* kzb = KZ + (size_t)bhn * 1024;
  float acc[4][4] = {};
  float accd[4] = {};
  for (int p = 0; p < 16; ++p) {
    __syncthreads();
#pragma unroll
    for (int j = 0; j < 4; ++j) {
      const int f = tid + 256 * j;
      float4 v4 = *(const float4*)(kvb + p * 4096 + 4 * f);
      *(float4*)&kvp[f >> 4][(f & 15) * 4] = v4;
    }
    if (tid < 64) kzp[tid] = kzb[p * 64 + tid];
    __syncthreads();
    float tqv[4];
#pragma unroll
    for (int ci = 0; ci < 4; ++ci) tqv[ci] = tqs[ty + 16 * ci][p];
    for (int e0 = 0; e0 < 64; e0 += 4) {
      float4 kz4 = *(const float4*)&kzp[e0];
      float4 kv0 = *(const float4*)&kvp[e0 + 0][tx * 4];
      float4 kv1 = *(const float4*)&kvp[e0 + 1][tx * 4];
      float4 kv2 = *(const float4*)&kvp[e0 + 2][tx * 4];
      float4 kv3 = *(const float4*)&kvp[e0 + 3][tx * 4];
#pragma unroll
      for (int ci = 0; ci < 4; ++ci) {
        float4 eq4 = *(const float4*)&eqs[ty + 16 * ci][e0];
        const float a0 = tqv[ci] * eq4.x, a1 = tqv[ci] * eq4.y;
        const float a2 = tqv[ci] * eq4.z, a3 = tqv[ci] * eq4.w;
        acc[ci][0] += a0 * kv0.x; acc[ci][1] += a0 * kv0.y; acc[ci][2] += a0 * kv0.z; acc[ci][3] += a0 * kv0.w;
        acc[ci][0] += a1 * kv1.x; acc[ci][1] += a1 * kv1.y; acc[ci][2] += a1 * kv1.z; acc[ci][3] += a1 * kv1.w;
        acc[ci][0] += a2 * kv2.x; acc[ci][1] += a2 * kv2.y; acc[ci][2] += a2 * kv2.z; acc[ci][3] += a2 * kv2.w;
        acc[ci][0] += a3 * kv3.x; acc[ci][1] += a3 * kv3.y; acc[ci][2] += a3 * kv3.z; acc[ci][3] += a3 * kv3.w;
        accd[ci] += a0 * kz4.x + a1 * kz4.y + a2 * kz4.z + a3 * kz4.w;
      }
    }
  }
#pragma unroll
  for (int ci = 0; ci < 4; ++ci) {
    const int rloc = ty + 16 * ci;
    const size_t row = rowbase + rloc;
    const int t = n * 128 + rh * 64 + rloc;
    const float invd = 1.f / (den[row] + accd[ci] + EPS_);
    float4 nm = *(const float4*)(numb + row * 64 + tx * 4);
    float4 o;
    o.x = (nm.x + acc[ci][0]) * invd;
    o.y = (nm.y + acc[ci][1]) * invd;
    o.z = (nm.z + acc[ci][2]) * invd;
    o.w = (nm.w + acc[ci][3]) * invd;
    *(float4*)(att + (size_t)(b * T_ + t) * 512 + h * 64 + tx * 4) = o;
  }
}

extern "C" void kernel_launch(void* const* d_in, const int* in_sizes, int n_in,
                              void* d_out, int out_size, void* d_ws, size_t ws_size,
                              hipStream_t stream) {
  const float* x   = (const float*)d_in[0];
  const float* Wq  = (const float*)d_in[1];
  const float* Wk  = (const float*)d_in[2];
  const float* Wv  = (const float*)d_in[3];
  const float* Wo  = (const float*)d_in[4];
  const float* prj = (const float*)d_in[5];
  const float* scl = (const float*)d_in[6];
  const int*   shh = (const int*)d_in[7];
  const float* sss = (const float*)d_in[8];

  float* ws  = (float*)d_ws;
  float* q   = ws;                 // [B,T,H,D] as [4096,512]
  float* k   = q + 2097152;
  float* v   = k + 2097152;
  float* Tq  = v + 2097152;        // [B,H,T,16]
  float* Eq  = Tq + 524288;        // [B,H,T,64]
  float* Tk  = Eq + 2097152;
  float* Ek  = Tk + 524288;
  float* vh  = Ek + 2097152;       // [B,H,T,64]
  float* KV  = vh + 2097152;       // [B,H,N,16,64,64]
  float* KZ  = KV + 16777216;      // [B,H,N,16,64]
  float* nmb = KZ + 262144;        // [B,H,T,64]
  float* den = nmb + 2097152;      // [B,H,T]
  float* att = den + 32768;        // [B,T,512]

  dim3 gg(64, 8);
  hipLaunchKernelGGL(gemm512, gg, dim3(256), 0, stream, x, Wq, q);
  hipLaunchKernelGGL(gemm512, gg, dim3(256), 0, stream, x, Wk, k);
  hipLaunchKernelGGL(gemm512, gg, dim3(256), 0, stream, x, Wv, v);
  hipLaunchKernelGGL(feat_kernel, dim3(256, 2), dim3(128), 0, stream,
                     q, k, v, prj, scl, shh, sss, Tq, Eq, Tk, Ek, vh);
  hipLaunchKernelGGL(kv_kernel, dim3(256, 4), dim3(256), 0, stream, Tk, Ek, vh, KV);
  hipLaunchKernelGGL(kz_kernel, dim3(256), dim3(256), 0, stream, Tk, Ek, KZ);
  hipLaunchKernelGGL(cumsum_kernel, dim3(4160), dim3(256), 0, stream, KV, KZ);
  hipLaunchKernelGGL(intra_kernel, dim3(256, 2), dim3(256), 0, stream, Tq, Eq, Tk, Ek, vh, nmb, den);
  hipLaunchKernelGGL(inter_kernel, dim3(256, 2), dim3(256), 0, stream, Tq, Eq, KV, KZ, nmb, den, att);
  hipLaunchKernelGGL(gemm512, gg, dim3(256), 0, stream, att, Wo, (float*)d_out);
}

// Round 5
// 406.608 us; speedup vs baseline: 1.2358x; 1.1830x over previous
//
#include <hip/hip_runtime.h>
#include <math.h>

#define B_ 2
#define T_ 2048
#define E_ 512
#define H_ 8
#define D_ 64
#define NCH 16
#define CH 128
#define EPS_ 1e-5f

// ---------------- GEMM: C[4096,512] = A[4096,512] @ W[512,512] (f32) ----------------
__global__ __launch_bounds__(256) void gemm512(const float* __restrict__ A,
                                               const float* __restrict__ W,
                                               float* __restrict__ C) {
  __shared__ float As[16][68];
  __shared__ float Bs[16][68];
  const int tid = threadIdx.x;
  const int tx = tid & 15, ty = tid >> 4;
  const int row0 = blockIdx.x * 64, col0 = blockIdx.y * 64;
  const int lr = tid >> 2, lk = (tid & 3) * 4;
  const int bkr = tid >> 4, bcc = (tid & 15) * 4;
  float acc[4][4] = {};
  for (int k0 = 0; k0 < 512; k0 += 16) {
    float4 a4 = *(const float4*)(A + (size_t)(row0 + lr) * 512 + k0 + lk);
    As[lk + 0][lr] = a4.x; As[lk + 1][lr] = a4.y;
    As[lk + 2][lr] = a4.z; As[lk + 3][lr] = a4.w;
    *(float4*)&Bs[bkr][bcc] = *(const float4*)(W + (size_t)(k0 + bkr) * 512 + col0 + bcc);
    __syncthreads();
#pragma unroll
    for (int kk = 0; kk < 16; ++kk) {
      float4 av = *(const float4*)&As[kk][ty * 4];
      float4 bv = *(const float4*)&Bs[kk][tx * 4];
      float aa[4] = {av.x, av.y, av.z, av.w};
      float bb[4] = {bv.x, bv.y, bv.z, bv.w};
#pragma unroll
      for (int i = 0; i < 4; ++i)
#pragma unroll
        for (int j = 0; j < 4; ++j) acc[i][j] += aa[i] * bb[j];
    }
    __syncthreads();
  }
#pragma unroll
  for (int i = 0; i < 4; ++i) {
    float4 o = make_float4(acc[i][0], acc[i][1], acc[i][2], acc[i][3]);
    *(float4*)(C + (size_t)(row0 + ty * 4 + i) * 512 + col0 + tx * 4) = o;
  }
}

// ---------------- features as tiled GEMMs: 128 rows/block, 256 threads ----------------
// Z[128x64] = U @ ProjT ; P[128x32] = U @ M12 ; then exp-scale (E) and circular conv (T)
__global__ __launch_bounds__(256) void feat_kernel(
    const float* __restrict__ q, const float* __restrict__ k,
    const float* __restrict__ proj, const float* __restrict__ scales,
    const int* __restrict__ sh, const float* __restrict__ ss,
    float* __restrict__ Tq, float* __restrict__ Eq,
    float* __restrict__ Tk, float* __restrict__ Ek) {
  __shared__ float Us[128][68];    // [row][d], normalized in place
  __shared__ float PjT[64][68];    // [d][m]
  __shared__ float MT[64][36];     // [d][j]: cols 0-15 sketch1, 16-31 sketch2
  __shared__ float Ps[128][36];    // [row][j]: p1 | p2
  __shared__ float csq[64], cmb[64], ccf[64];
  const int tid = threadIdx.x;
  const int isK = blockIdx.y;
  const float* in = (isK ? k : q) + (size_t)blockIdx.x * 8192;
  float* To = isK ? Tk : Tq;
  float* Eo = isK ? Ek : Eq;

  // stage input rows (contiguous region), proj transposed, zero MT
#pragma unroll
  for (int j = 0; j < 8; ++j) {
    const int f = tid + 256 * j;
    float4 a = *(const float4*)(in + 4 * f);
    *(float4*)&Us[f >> 4][(f & 15) * 4] = a;
  }
  for (int i = tid; i < 4096; i += 256) PjT[i & 63][i >> 6] = proj[i];
  for (int i = tid; i < 64 * 36; i += 256) (&MT[0][0])[i] = 0.f;
  __syncthreads();

  // scatter sketch into MT; per-column constants
  if (tid < 64) {
    MT[tid][sh[tid]] = ss[tid];
    MT[tid][16 + sh[64 + tid]] = ss[64 + tid];
  } else if (tid < 128) {
    const int c = tid - 64;
    const float t = scales[(c >> 4) * 2], cc = scales[(c >> 4) * 2 + 1];
    csq[c] = sqrtf(2.f * t); cmb[c] = -2.f * t; ccf[c] = sqrtf(cc / 16.f);
  }
  // normalize rows: 2 threads per row, shuffle-combined
  {
    const int r2 = tid >> 1, hf = tid & 1;
    float4 tv[8]; float s2 = 0.f;
#pragma unroll
    for (int j2 = 0; j2 < 8; ++j2) {
      tv[j2] = *(const float4*)&Us[r2][hf * 32 + 4 * j2];
      s2 += tv[j2].x * tv[j2].x + tv[j2].y * tv[j2].y + tv[j2].z * tv[j2].z + tv[j2].w * tv[j2].w;
    }
    s2 += __shfl_xor(s2, 1);
    const float inv = 1.f / (sqrtf(s2) + 1e-6f);
#pragma unroll
    for (int j2 = 0; j2 < 8; ++j2) {
      tv[j2].x *= inv; tv[j2].y *= inv; tv[j2].z *= inv; tv[j2].w *= inv;
      *(float4*)&Us[r2][hf * 32 + 4 * j2] = tv[j2];
    }
  }
  __syncthreads();

  // fused register-tiled GEMMs: rows ty+32i, Z cols tx*8..+8, P cols tx*4..+4
  const int tx = tid & 7, ty = tid >> 3;
  const int c0 = tx * 8, pc0 = tx * 4;
  float accz[4][8] = {};
  float accp[4][4] = {};
  for (int d0 = 0; d0 < 64; d0 += 4) {
    float Aar[4][4];
#pragma unroll
    for (int i = 0; i < 4; ++i) {
      float4 a4 = *(const float4*)&Us[ty + 32 * i][d0];
      Aar[i][0] = a4.x; Aar[i][1] = a4.y; Aar[i][2] = a4.z; Aar[i][3] = a4.w;
    }
#pragma unroll
    for (int dd = 0; dd < 4; ++dd) {
      float4 bl = *(const float4*)&PjT[d0 + dd][c0];
      float4 bh = *(const float4*)&PjT[d0 + dd][c0 + 4];
      float4 bm = *(const float4*)&MT[d0 + dd][pc0];
      float bb[8] = {bl.x, bl.y, bl.z, bl.w, bh.x, bh.y, bh.z, bh.w};
      float bp[4] = {bm.x, bm.y, bm.z, bm.w};
#pragma unroll
      for (int i = 0; i < 4; ++i) {
        const float a = Aar[i][dd];
#pragma unroll
        for (int j = 0; j < 8; ++j) accz[i][j] += a * bb[j];
#pragma unroll
        for (int j = 0; j < 4; ++j) accp[i][j] += a * bp[j];
      }
    }
  }

  // epilogue: E = exp(sq*z+mb)*cf (coalesced), P -> LDS
  float sq8[8], mb8[8], cf8[8];
#pragma unroll
  for (int j = 0; j < 8; ++j) { sq8[j] = csq[c0 + j]; mb8[j] = cmb[c0 + j]; cf8[j] = ccf[c0 + j]; }
  const int bx16 = blockIdx.x * 16;
#pragma unroll
  for (int i = 0; i < 4; ++i) {
    const int r = ty + 32 * i;
    const int bt = bx16 + (r >> 3);
    const size_t orow = (size_t)((bt >> 11) * 8 + (r & 7)) * 2048 + (bt & 2047);
    float e[8];
#pragma unroll
    for (int j = 0; j < 8; ++j) e[j] = expf(sq8[j] * accz[i][j] + mb8[j]) * cf8[j];
    *(float4*)(Eo + orow * 64 + c0) = make_float4(e[0], e[1], e[2], e[3]);
    *(float4*)(Eo + orow * 64 + c0 + 4) = make_float4(e[4], e[5], e[6], e[7]);
    *(float4*)&Ps[r][pc0] = make_float4(accp[i][0], accp[i][1], accp[i][2], accp[i][3]);
  }
  __syncthreads();

  // TensorSketch circular conv: 2 threads/row, 8 outputs each, static indices
  const int rr = tid >> 1, hf2 = tid & 1;
  float p1v[16], p2v[16];
#pragma unroll
  for (int j4 = 0; j4 < 4; ++j4) {
    float4 a = *(const float4*)&Ps[rr][j4 * 4];
    p1v[j4 * 4 + 0] = a.x; p1v[j4 * 4 + 1] = a.y; p1v[j4 * 4 + 2] = a.z; p1v[j4 * 4 + 3] = a.w;
    float4 b2 = *(const float4*)&Ps[rr][16 + j4 * 4];
    p2v[j4 * 4 + 0] = b2.x; p2v[j4 * 4 + 1] = b2.y; p2v[j4 * 4 + 2] = b2.z; p2v[j4 * 4 + 3] = b2.w;
  }
  const int bt2 = bx16 + (rr >> 3);
  const size_t orow2 = (size_t)((bt2 >> 11) * 8 + (rr & 7)) * 2048 + (bt2 & 2047);
  float tout[8];
  if (hf2 == 0) {
#pragma unroll
    for (int r8 = 0; r8 < 8; ++r8) {
      float a = 0.f;
#pragma unroll
      for (int j = 0; j < 16; ++j) a += p1v[j] * p2v[(r8 - j) & 15];
      tout[r8] = a;
    }
  } else {
#pragma unroll
    for (int r8 = 0; r8 < 8; ++r8) {
      float a = 0.f;
#pragma unroll
      for (int j = 0; j < 16; ++j) a += p1v[j] * p2v[(8 + r8 - j) & 15];
      tout[r8] = a;
    }
  }
  *(float4*)(To + orow2 * 16 + hf2 * 8) = make_float4(tout[0], tout[1], tout[2], tout[3]);
  *(float4*)(To + orow2 * 16 + hf2 * 8 + 4) = make_float4(tout[4], tout[5], tout[6], tout[7]);
}

// ---------------- v relayout [b,t,h,d] -> [b,h,t,d], float4 ----------------
__global__ __launch_bounds__(256) void vrelayout(const float* __restrict__ v, float* __restrict__ vh) {
  const int f = blockIdx.x * 256 + threadIdx.x;   // float4 index, 524288 total
  float4 a = *(const float4*)(v + 4 * (size_t)f);
  const int d4 = f & 15, h = (f >> 4) & 7, bt = f >> 7;
  const size_t orow = (size_t)((bt >> 11) * 8 + h) * 2048 + (bt & 2047);
  *(float4*)(vh + orow * 64 + d4 * 4) = a;
}

// ---------------- per-chunk KV[p,e,d] (e-slice of 16 per block), vectorized LDS ----------------
__global__ __launch_bounds__(256) void kv_kernel(const float* __restrict__ Tk, const float* __restrict__ Ek,
                                                 const float* __restrict__ vh, float* __restrict__ KV) {
  const int bhn = blockIdx.x;      // bh*16 + n
  const int slice = blockIdx.y;    // e0 = slice*16
  __shared__ float tks[128][20];   // pad 20: float4-aligned rows
  __shared__ float eks[128][16];
  __shared__ float vs[128][64];
  const int tid = threadIdx.x;
  const size_t rowbase = (size_t)bhn * 128;
  for (int i = tid; i < 2048; i += 256) tks[i >> 4][i & 15] = Tk[rowbase * 16 + i];
  for (int i = tid; i < 2048; i += 256) { int r = i >> 4, e = i & 15; eks[r][e] = Ek[(rowbase + r) * 64 + slice * 16 + e]; }
  for (int i = tid; i < 2048; i += 256) {
    float4 v4 = *(const float4*)(vh + rowbase * 64 + 4 * i);
    *(float4*)&vs[(4 * i) >> 6][(4 * i) & 63] = v4;
  }
  __syncthreads();
  const int d = tid & 63, er = tid >> 6;
  float acc[4][16] = {};
  for (int c = 0; c < 128; ++c) {
    float4 t0 = *(const float4*)&tks[c][0];
    float4 t1 = *(const float4*)&tks[c][4];
    float4 t2 = *(const float4*)&tks[c][8];
    float4 t3 = *(const float4*)&tks[c][12];
    float tkc[16] = {t0.x, t0.y, t0.z, t0.w, t1.x, t1.y, t1.z, t1.w,
                     t2.x, t2.y, t2.z, t2.w, t3.x, t3.y, t3.z, t3.w};
    float4 e4 = *(const float4*)&eks[c][er * 4];
    const float w = vs[c][d];
    float ai[4] = {e4.x * w, e4.y * w, e4.z * w, e4.w * w};
#pragma unroll
    for (int i = 0; i < 4; ++i)
#pragma unroll
      for (int p = 0; p < 16; ++p) acc[i][p] += tkc[p] * ai[i];
  }
  float* out = KV + (size_t)bhn * 65536;
#pragma unroll
  for (int i = 0; i < 4; ++i)
#pragma unroll
    for (int p = 0; p < 16; ++p)
      out[(size_t)(p * 64 + slice * 16 + er * 4 + i) * 64 + d] = acc[i][p];
}

// ---------------- per-chunk KZ[p,e] ----------------
__global__ __launch_bounds__(256) void kz_kernel(const float* __restrict__ Tk, const float* __restrict__ Ek,
                                                 float* __restrict__ KZ) {
  const int bhn = blockIdx.x;
  __shared__ float tks[128][20];
  __shared__ float eks[128][64];
  const int tid = threadIdx.x;
  const size_t rowbase = (size_t)bhn * 128;
  for (int i = tid; i < 2048; i += 256) tks[i >> 4][i & 15] = Tk[rowbase * 16 + i];
  for (int i = tid; i < 2048; i += 256) {
    float4 v4 = *(const float4*)(Ek + rowbase * 64 + 4 * i);
    *(float4*)&eks[(4 * i) >> 6][(4 * i) & 63] = v4;
  }
  __syncthreads();
  const int e = tid & 63, p0 = (tid >> 6) * 4;
  float a[4] = {};
  for (int c = 0; c < 128; ++c) {
    float4 t4 = *(const float4*)&tks[c][p0];
    const float ek = eks[c][e];
    a[0] += t4.x * ek; a[1] += t4.y * ek; a[2] += t4.z * ek; a[3] += t4.w * ek;
  }
#pragma unroll
  for (int j = 0; j < 4; ++j) KZ[(size_t)bhn * 1024 + (p0 + j) * 64 + e] = a[j];
}

// ---------------- exclusive cumsum over chunks (in place) ----------------
__global__ void cumsum_kernel(float* __restrict__ KV, float* __restrict__ KZ) {
  const size_t idx = (size_t)blockIdx.x * 256 + threadIdx.x;
  const size_t nkv = (size_t)B_ * H_ * 65536;
  if (idx < nkv) {
    const size_t bh = idx >> 16, j = idx & 65535;
    float* p = KV + bh * NCH * 65536 + j;
    float a = 0.f;
#pragma unroll
    for (int n = 0; n < NCH; ++n) { const float t = p[(size_t)n << 16]; p[(size_t)n << 16] = a; a += t; }
  } else {
    const size_t i2 = idx - nkv;
    if (i2 < (size_t)B_ * H_ * 1024) {
      const size_t bh = i2 >> 10, j = i2 & 1023;
      float* p = KZ + bh * NCH * 1024 + j;
      float a = 0.f;
#pragma unroll
      for (int n = 0; n < NCH; ++n) { const float t = p[n << 10]; p[n << 10] = a; a += t; }
    }
  }
}

// ---------------- intra-chunk causal part, single-sync safe version ----------------
__global__ __launch_bounds__(256) void intra_kernel(const float* __restrict__ Tq, const float* __restrict__ Eq,
                                                    const float* __restrict__ Tk, const float* __restrict__ Ek,
                                                    const float* __restrict__ vh,
                                                    float* __restrict__ numb, float* __restrict__ den) {
  const int bhn = blockIdx.x;
  const int rh = blockIdx.y;
  __shared__ float tks[128][20];   // [k][p], padded
  __shared__ float eks[128][68];   // [k][e], padded
  __shared__ float vs[128][68];    // [k][d], padded
  const int tid = threadIdx.x;
  const int r = tid >> 2, dg = tid & 3, d0 = dg * 16;
  const int nk = (rh + 1) * 64;            // k rows needed (block-uniform)
  const size_t chunkbase = (size_t)bhn * 128;
  const size_t myrow = chunkbase + rh * 64 + r;

  for (int i = tid; i < nk * 16; i += 256) tks[i >> 4][i & 15] = Tk[chunkbase * 16 + i];
  for (int i = tid; i < nk * 16; i += 256) {
    float4 e4 = *(const float4*)(Ek + chunkbase * 64 + 4 * i);
    *(float4*)&eks[(4 * i) >> 6][(4 * i) & 63] = e4;
    float4 w4 = *(const float4*)(vh + chunkbase * 64 + 4 * i);
    *(float4*)&vs[(4 * i) >> 6][(4 * i) & 63] = w4;
  }
  float tq[16], eq[64];
#pragma unroll
  for (int pp = 0; pp < 4; ++pp) {
    float4 t4 = *(const float4*)(Tq + myrow * 16 + pp * 4);
    tq[pp * 4 + 0] = t4.x; tq[pp * 4 + 1] = t4.y; tq[pp * 4 + 2] = t4.z; tq[pp * 4 + 3] = t4.w;
  }
#pragma unroll
  for (int ee = 0; ee < 16; ++ee) {
    float4 e4 = *(const float4*)(Eq + myrow * 64 + ee * 4);
    eq[ee * 4 + 0] = e4.x; eq[ee * 4 + 1] = e4.y; eq[ee * 4 + 2] = e4.z; eq[ee * 4 + 3] = e4.w;
  }
  __syncthreads();

  float num[16] = {};
  float dn = 0.f;
  const int kmax = rh * 64 + r;            // inclusive causal bound
  for (int kk = 0; kk <= kmax; ++kk) {
    float dT = 0.f, dE = 0.f;
#pragma unroll
    for (int pp = 0; pp < 4; ++pp) {
      float4 t4 = *(const float4*)&tks[kk][pp * 4];
      dT += tq[pp * 4 + 0] * t4.x + tq[pp * 4 + 1] * t4.y + tq[pp * 4 + 2] * t4.z + tq[pp * 4 + 3] * t4.w;
    }
#pragma unroll
    for (int ee = 0; ee < 16; ++ee) {
      float4 e4 = *(const float4*)&eks[kk][ee * 4];
      dE += eq[ee * 4 + 0] * e4.x + eq[ee * 4 + 1] * e4.y + eq[ee * 4 + 2] * e4.z + eq[ee * 4 + 3] * e4.w;
    }
    const float s = dT * dE;
    dn += s;
#pragma unroll
    for (int jj = 0; jj < 4; ++jj) {
      float4 v4 = *(const float4*)&vs[kk][d0 + jj * 4];
      num[jj * 4 + 0] += s * v4.x; num[jj * 4 + 1] += s * v4.y;
      num[jj * 4 + 2] += s * v4.z; num[jj * 4 + 3] += s * v4.w;
    }
  }
#pragma unroll
  for (int jj = 0; jj < 4; ++jj) {
    float4 o = make_float4(num[jj * 4 + 0], num[jj * 4 + 1], num[jj * 4 + 2], num[jj * 4 + 3]);
    *(float4*)(numb + myrow * 64 + d0 + jj * 4) = o;
  }
  if (dg == 0) den[myrow] = dn;
}

// ---------------- inter-chunk part + finalize, single-buffered safe version ----------------
__global__ __launch_bounds__(256) void inter_kernel(const float* __restrict__ Tq, const float* __restrict__ Eq,
                                                    const float* __restrict__ KV, const float* __restrict__ KZ,
                                                    const float* __restrict__ numb, const float* __restrict__ den,
                                                    float* __restrict__ att) {
  const int bhn = blockIdx.x;
  const int rh = blockIdx.y;
  const int n = bhn & 15, bh = bhn >> 4;
  const int b = bh >> 3, h = bh & 7;
  __shared__ float tqs[64][17];
  __shared__ float eqs[64][68];
  __shared__ float kvp[64][68];
  __shared__ float kzp[64];
  const int tid = threadIdx.x;
  const int tx = tid & 15, ty = tid >> 4;
  const size_t rowbase = (size_t)bhn * 128 + rh * 64;
  for (int i = tid; i < 1024; i += 256) tqs[i >> 4][i & 15] = Tq[rowbase * 16 + i];
  for (int i = tid; i < 1024; i += 256) {
    float4 v4 = *(const float4*)(Eq + rowbase * 64 + 4 * i);
    *(float4*)&eqs[i >> 4][(i & 15) * 4] = v4;
  }
  const float* kvb = KV + (size_t)bhn * 65536;
  const float* kzb = KZ + (size_t)bhn * 1024;
  float acc[4][4] = {};
  float accd[4] = {};
  for (int p = 0; p < 16; ++p) {
    __syncthreads();
#pragma unroll
    for (int j = 0; j < 4; ++j) {
      const int f = tid + 256 * j;
      float4 v4 = *(const float4*)(kvb + p * 4096 + 4 * f);
      *(float4*)&kvp[f >> 4][(f & 15) * 4] = v4;
    }
    if (tid < 64) kzp[tid] = kzb[p * 64 + tid];
    __syncthreads();
    float tqv[4];
#pragma unroll
    for (int ci = 0; ci < 4; ++ci) tqv[ci] = tqs[ty + 16 * ci][p];
    for (int e0 = 0; e0 < 64; e0 += 4) {
      float4 kz4 = *(const float4*)&kzp[e0];
      float4 kv0 = *(const float4*)&kvp[e0 + 0][tx * 4];
      float4 kv1 = *(const float4*)&kvp[e0 + 1][tx * 4];
      float4 kv2 = *(const float4*)&kvp[e0 + 2][tx * 4];
      float4 kv3 = *(const float4*)&kvp[e0 + 3][tx * 4];
#pragma unroll
      for (int ci = 0; ci < 4; ++ci) {
        float4 eq4 = *(const float4*)&eqs[ty + 16 * ci][e0];
        const float a0 = tqv[ci] * eq4.x, a1 = tqv[ci] * eq4.y;
        const float a2 = tqv[ci] * eq4.z, a3 = tqv[ci] * eq4.w;
        acc[ci][0] += a0 * kv0.x; acc[ci][1] += a0 * kv0.y; acc[ci][2] += a0 * kv0.z; acc[ci][3] += a0 * kv0.w;
        acc[ci][0] += a1 * kv1.x; acc[ci][1] += a1 * kv1.y; acc[ci][2] += a1 * kv1.z; acc[ci][3] += a1 * kv1.w;
        acc[ci][0] += a2 * kv2.x; acc[ci][1] += a2 * kv2.y; acc[ci][2] += a2 * kv2.z; acc[ci][3] += a2 * kv2.w;
        acc[ci][0] += a3 * kv3.x; acc[ci][1] += a3 * kv3.y; acc[ci][2] += a3 * kv3.z; acc[ci][3] += a3 * kv3.w;
        accd[ci] += a0 * kz4.x + a1 * kz4.y + a2 * kz4.z + a3 * kz4.w;
      }
    }
  }
#pragma unroll
  for (int ci = 0; ci < 4; ++ci) {
    const int rloc = ty + 16 * ci;
    const size_t row = rowbase + rloc;
    const int t = n * 128 + rh * 64 + rloc;
    const float invd = 1.f / (den[row] + accd[ci] + EPS_);
    float4 nm = *(const float4*)(numb + row * 64 + tx * 4);
    float4 o;
    o.x = (nm.x + acc[ci][0]) * invd;
    o.y = (nm.y + acc[ci][1]) * invd;
    o.z = (nm.z + acc[ci][2]) * invd;
    o.w = (nm.w + acc[ci][3]) * invd;
    *(float4*)(att + (size_t)(b * T_ + t) * 512 + h * 64 + tx * 4) = o;
  }
}

extern "C" void kernel_launch(void* const* d_in, const int* in_sizes, int n_in,
                              void* d_out, int out_size, void* d_ws, size_t ws_size,
                              hipStream_t stream) {
  const float* x   = (const float*)d_in[0];
  const float* Wq  = (const float*)d_in[1];
  const float* Wk  = (const float*)d_in[2];
  const float* Wv  = (const float*)d_in[3];
  const float* Wo  = (const float*)d_in[4];
  const float* prj = (const float*)d_in[5];
  const float* scl = (const float*)d_in[6];
  const int*   shh = (const int*)d_in[7];
  const float* sss = (const float*)d_in[8];

  float* ws  = (float*)d_ws;
  float* q   = ws;                 // [B,T,H,D] as [4096,512]
  float* k   = q + 2097152;
  float* v   = k + 2097152;
  float* Tq  = v + 2097152;        // [B,H,T,16]
  float* Eq  = Tq + 524288;        // [B,H,T,64]
  float* Tk  = Eq + 2097152;
  float* Ek  = Tk + 524288;
  float* vh  = Ek + 2097152;       // [B,H,T,64]
  float* KV  = vh + 2097152;       // [B,H,N,16,64,64]
  float* KZ  = KV + 16777216;      // [B,H,N,16,64]
  float* nmb = KZ + 262144;        // [B,H,T,64]
  float* den = nmb + 2097152;      // [B,H,T]
  float* att = den + 32768;        // [B,T,512]

  dim3 gg(64, 8);
  hipLaunchKernelGGL(gemm512, gg, dim3(256), 0, stream, x, Wq, q);
  hipLaunchKernelGGL(gemm512, gg, dim3(256), 0, stream, x, Wk, k);
  hipLaunchKernelGGL(gemm512, gg, dim3(256), 0, stream, x, Wv, v);
  hipLaunchKernelGGL(feat_kernel, dim3(256, 2), dim3(256), 0, stream,
                     q, k, prj, scl, shh, sss, Tq, Eq, Tk, Ek);
  hipLaunchKernelGGL(vrelayout, dim3(2048), dim3(256), 0, stream, v, vh);
  hipLaunchKernelGGL(kv_kernel, dim3(256, 4), dim3(256), 0, stream, Tk, Ek, vh, KV);
  hipLaunchKernelGGL(kz_kernel, dim3(256), dim3(256), 0, stream, Tk, Ek, KZ);
  hipLaunchKernelGGL(cumsum_kernel, dim3(4160), dim3(256), 0, stream, KV, KZ);
  hipLaunchKernelGGL(intra_kernel, dim3(256, 2), dim3(256), 0, stream, Tq, Eq, Tk, Ek, vh, nmb, den);
  hipLaunchKernelGGL(inter_kernel, dim3(256, 2), dim3(256), 0, stream, Tq, Eq, KV, KZ, nmb, den, att);
  hipLaunchKernelGGL(gemm512, gg, dim3(256), 0, stream, att, Wo, (float*)d_out);
}